// Round 1
// baseline (222.218 us; speedup 1.0000x reference)
//
#include <hip/hip_runtime.h>

#define S_LEN 2048
#define DHEAD 64
#define BATCH 4
#define NHEAD 16
#define QBLK 64
#define KBLK 64
#define NWORDS (BATCH * S_LEN * (S_LEN / 64))  // 262144 u64 words = 2 MB

typedef __attribute__((ext_vector_type(4))) float f32x4;
typedef __attribute__((ext_vector_type(4))) int i32x4;
typedef __attribute__((ext_vector_type(8))) short short8v;
typedef __attribute__((ext_vector_type(4))) short short4v;

// fp32 -> bf16 (RNE), finite inputs only
static __device__ __forceinline__ short f2bf(float x) {
  unsigned u = __float_as_uint(x);
  u += 0x7fffu + ((u >> 16) & 1u);
  return (short)(u >> 16);
}

// D = A*B + C, 16x16x32 bf16 MFMA via inline asm (operand regs as i32 quads)
static __device__ __forceinline__ void mfma16(const i32x4& a, const i32x4& b, f32x4& c) {
  asm("v_mfma_f32_16x16x32_bf16 %0, %1, %2, %0" : "+v"(c) : "v"(a), "v"(b));
}

// Pack int32 0/1 mask into bitmask: bit k of word w = mask[w*64+k] != 0
__global__ __launch_bounds__(256) void pack_mask_kernel(
    const int* __restrict__ mask, unsigned long long* __restrict__ packed, int nwords) {
  int wid = blockIdx.x * (blockDim.x >> 6) + (threadIdx.x >> 6);
  int lane = threadIdx.x & 63;
  int stride = gridDim.x * (blockDim.x >> 6);
  for (int w = wid; w < nwords; w += stride) {
    int m = mask[(size_t)w * 64 + lane];
    unsigned long long bits = __ballot(m != 0);
    if (lane == 0) packed[w] = bits;
  }
}

template <bool PACKED>
__global__ __launch_bounds__(256) void attn_kernel(
    const float* __restrict__ q, const float* __restrict__ k, const float* __restrict__ v,
    const unsigned long long* __restrict__ mpack, const int* __restrict__ mraw,
    float* __restrict__ out) {
  // LDS: K [key][d] bf16 swizzled; Vt [d][key] bf16 swizzled; per-wave P [q][key] swizzled
  __shared__ short Klds[64 * 64];
  __shared__ short Vtlds[64 * 64];
  __shared__ short Plds[4][16 * 64];

  const int tid = threadIdx.x;
  const int lane = tid & 63;
  const int wave = tid >> 6;
  const int l15 = lane & 15;
  const int l4 = lane >> 4;  // 0..3

  // XCD-aware decomposition: all 32 q-blocks of one head on one XCD
  const int id = blockIdx.x;
  const int work = (id & 7) * 256 + (id >> 3);  // bijective, 2048 % 8 == 0
  const int head = work >> 5;                   // 0..63 = b*16+h
  const int qb = (work & 31) * QBLK;
  const int b = head >> 4;

  const float* qbase = q + ((size_t)head * S_LEN + qb) * DHEAD;
  const float* kbase = k + (size_t)head * S_LEN * DHEAD;
  const float* vbase = v + (size_t)head * S_LEN * DHEAD;
  float* obase = out + ((size_t)head * S_LEN + qb) * DHEAD;

  const int qrow_w = wave * 16 + l15;  // this lane's q row (softmax/B-frag view)

  // ---- load Q fragments once, scale folded (B operand: n=l15 row, k=(l4*8+i)+32*ch) ----
  i32x4 qfrag[2];
  {
    const float* qp = qbase + (size_t)qrow_w * DHEAD + l4 * 8;
#pragma unroll
    for (int ch = 0; ch < 2; ++ch) {
      const f32x4* p = (const f32x4*)(qp + ch * 32);
      f32x4 a = p[0], c = p[1];
      short t[8];
#pragma unroll
      for (int i = 0; i < 4; ++i) t[i] = f2bf(a[i] * 0.125f);
#pragma unroll
      for (int i = 0; i < 4; ++i) t[4 + i] = f2bf(c[i] * 0.125f);
      i32x4 w;
#pragma unroll
      for (int i = 0; i < 4; ++i)
        w[i] = (int)((unsigned short)t[2 * i] | ((unsigned)(unsigned short)t[2 * i + 1] << 16));
      qfrag[ch] = w;
    }
  }

  const unsigned long long* mprow = nullptr;
  const int* mrrow = nullptr;
  if constexpr (PACKED)
    mprow = mpack + ((size_t)b * S_LEN + qb + qrow_w) * (S_LEN / 64);
  else
    mrrow = mraw + ((size_t)b * S_LEN + qb + qrow_w) * S_LEN;

  float m_run = -INFINITY, l_run = 0.f;
  f32x4 oacc[4] = {f32x4{0,0,0,0}, f32x4{0,0,0,0}, f32x4{0,0,0,0}, f32x4{0,0,0,0}};

  for (int kb = 0; kb < S_LEN / KBLK; ++kb) {
    // ---- stage K tile [64 key][64 d] -> bf16, chunk-swizzled ----
#pragma unroll
    for (int it = 0; it < 2; ++it) {
      int g = tid + it * 256;
      int r = g >> 3, c = g & 7;
      const f32x4* src = (const f32x4*)(kbase + (size_t)(kb * KBLK + r) * DHEAD + c * 8);
      f32x4 a = src[0], d2 = src[1];
      short8v w;
#pragma unroll
      for (int i = 0; i < 4; ++i) w[i] = f2bf(a[i]);
#pragma unroll
      for (int i = 0; i < 4; ++i) w[4 + i] = f2bf(d2[i]);
      *(short8v*)&Klds[r * 64 + (((c ^ (r & 7)) << 3))] = w;
    }
    // ---- stage V tile transposed: Vt[d][key], coalesced global reads ----
#pragma unroll
    for (int it = 0; it < 2; ++it) {
      int dcol = tid & 63;
      int kc = (tid >> 6) + it * 4;  // key chunk of 8
      short8v w;
#pragma unroll
      for (int i = 0; i < 8; ++i)
        w[i] = f2bf(vbase[(size_t)(kb * KBLK + kc * 8 + i) * DHEAD + dcol]);
      *(short8v*)&Vtlds[dcol * 64 + (((kc ^ (dcol & 7)) << 3))] = w;
    }
    __syncthreads();

    // ---- QK^T: mfma(K, Q) -> scores[key=(l4*4+r)][q=l15], masked ----
    unsigned long long mword = 0;
    if constexpr (PACKED) mword = mprow[kb];
    float sc[16];
#pragma unroll
    for (int kt = 0; kt < 4; ++kt) {
      f32x4 acc = {0.f, 0.f, 0.f, 0.f};
      int krow = kt * 16 + l15;
#pragma unroll
      for (int ch = 0; ch < 2; ++ch) {
        i32x4 af = *(const i32x4*)&Klds[krow * 64 + ((((ch * 4 + l4)) ^ (krow & 7)) << 3)];
        mfma16(af, qfrag[ch], acc);
      }
      unsigned bits;
      if constexpr (PACKED) {
        bits = (unsigned)(mword >> (kt * 16 + l4 * 4)) & 0xFu;
      } else {
        i32x4 mv = *(const i32x4*)(mrrow + kb * KBLK + kt * 16 + l4 * 4);
        bits = (mv[0] != 0 ? 1u : 0u) | (mv[1] != 0 ? 2u : 0u) |
               (mv[2] != 0 ? 4u : 0u) | (mv[3] != 0 ? 8u : 0u);
      }
#pragma unroll
      for (int r = 0; r < 4; ++r)
        sc[kt * 4 + r] = ((bits >> r) & 1u) ? acc[r] : -1e9f;
    }

    // ---- online softmax (per q=l15; 4 lanes/q reduced via shfl_xor 16,32) ----
    float mb = sc[0];
#pragma unroll
    for (int i = 1; i < 16; ++i) mb = fmaxf(mb, sc[i]);
    mb = fmaxf(mb, __shfl_xor(mb, 16));
    mb = fmaxf(mb, __shfl_xor(mb, 32));
    float mnew = fmaxf(m_run, mb);
    float alpha = __expf(m_run - mnew);
    float p[16], ps = 0.f;
#pragma unroll
    for (int i = 0; i < 16; ++i) { p[i] = __expf(sc[i] - mnew); ps += p[i]; }
    ps += __shfl_xor(ps, 16);
    ps += __shfl_xor(ps, 32);
    l_run = l_run * alpha + ps;
    m_run = mnew;
    // rescale O accumulator (acc rows are q=l4*4+r -> gather alpha via shfl)
#pragma unroll
    for (int r = 0; r < 4; ++r) {
      float ar = __shfl(alpha, l4 * 4 + r);
#pragma unroll
      for (int dt = 0; dt < 4; ++dt) oacc[dt][r] *= ar;
    }

    // ---- P -> LDS bf16 (row q=l15, cols kt*16+l4*4..+3), swizzled ----
#pragma unroll
    for (int kt = 0; kt < 4; ++kt) {
      short4v w;
#pragma unroll
      for (int r = 0; r < 4; ++r) w[r] = f2bf(p[kt * 4 + r]);
      int col = kt * 16 + l4 * 4;
      int chunk = col >> 3, within = col & 7;
      *(short4v*)&Plds[wave][l15 * 64 + ((chunk ^ (l15 & 7)) << 3) + within] = w;
    }

    // ---- PV: O[q][d] += P[q][key] * V[key][d]  (A=P, B from Vt rows) ----
    i32x4 pa[2];
#pragma unroll
    for (int ch = 0; ch < 2; ++ch)
      pa[ch] = *(const i32x4*)&Plds[wave][l15 * 64 + (((ch * 4 + l4) ^ (l15 & 7)) << 3)];
#pragma unroll
    for (int dt = 0; dt < 4; ++dt) {
      int drow = dt * 16 + l15;
#pragma unroll
      for (int ch = 0; ch < 2; ++ch) {
        i32x4 bf = *(const i32x4*)&Vtlds[drow * 64 + (((ch * 4 + l4) ^ (drow & 7)) << 3)];
        mfma16(pa[ch], bf, oacc[dt]);
      }
    }
    __syncthreads();
  }

  // ---- epilogue: normalize and store (lane holds q=l4*4+r, d=dt*16+l15) ----
#pragma unroll
  for (int r = 0; r < 4; ++r) {
    float inv = 1.f / __shfl(l_run, l4 * 4 + r);
    float* op = obase + (size_t)(wave * 16 + l4 * 4 + r) * DHEAD + l15;
#pragma unroll
    for (int dt = 0; dt < 4; ++dt) op[dt * 16] = oacc[dt][r] * inv;
  }
}

extern "C" void kernel_launch(void* const* d_in, const int* in_sizes, int n_in,
                              void* d_out, int out_size, void* d_ws, size_t ws_size,
                              hipStream_t stream) {
  const float* q = (const float*)d_in[0];
  const float* k = (const float*)d_in[1];
  const float* v = (const float*)d_in[2];
  const int* mask = (const int*)d_in[3];
  float* out = (float*)d_out;

  if (ws_size >= (size_t)NWORDS * 8) {
    unsigned long long* mp = (unsigned long long*)d_ws;
    pack_mask_kernel<<<1024, 256, 0, stream>>>(mask, mp, NWORDS);
    attn_kernel<true><<<2048, 256, 0, stream>>>(q, k, v, mp, nullptr, out);
  } else {
    attn_kernel<false><<<2048, 256, 0, stream>>>(q, k, v, nullptr, mask, out);
  }
}